// Round 17
// baseline (123.213 us; speedup 1.0000x reference)
//
#include <hip/hip_runtime.h>

// VectorQuantizer on MI355X (gfx950) — REGISTER-DIRECT MFMA argmin: E-fragments
// stream from L2 into registers (no LDS, no barriers in hot loop); A-fragments
// hoisted once.  Fused quantized write; f64 exact refine patches near-ties.
// R17: block = 256 thr = 4 waves = 128 pts.  Wave w owns pts [w*32..+32) x ALL
// 512 codes (16-code steps): loop = {4 global b128 B-loads + 1 enorm load +
// 12 MFMA + packed-u32 min} — fully unrollable, compiler pipelines loads.
// No cross-wave merge.  LDS 32 KiB (X staging only; aliased for hist/fidx).
//
// Distance core: s = ||e||^2 - 2 x.e.  E pre-scaled by 2048, f16 hi/lo split,
// stored LINEAR in ws (direct per-lane b128 reads).  X = f16 hi/lo of (-2x).
// 3-term MFMA (xh.eh + xh.el + xl.eh).  C-init = (||e||^2+256)*2048; packed
// key ((uint)acc << 9) | idx -> u32-min argmin, first-min tie-break.
// Near-ties (gap < 21/2048) re-solved in f64 by vq_refine (patches idx AND
// quantized rows).  Loss = Sum(s) + Sum(xnorm), per-wave register partials.

typedef __attribute__((ext_vector_type(8))) _Float16 f16x8;
typedef __attribute__((ext_vector_type(4))) float f32x4;
typedef unsigned int uint;
typedef unsigned short ushort;

namespace {
constexpr int kC = 64, kH = 64, kW = 64;
constexpr int kK = 512, kD = 64;
constexpr int kHW = kH * kW;                  // 4096
constexpr int kCHW = kC * kHW;                // 262144
constexpr int kN = 32 * kHW;                  // 131072
constexpr int kQElems = 32 * kC * kHW;        // 8388608
constexpr uint kGapFP = 21u;                  // 0.0103 in 1/2048 units
}

__device__ __forceinline__ ushort hb(_Float16 h) { return __builtin_bit_cast(ushort, h); }
__device__ __forceinline__ uint umin(uint a, uint b) { return a < b ? a : b; }
__device__ __forceinline__ uint umax(uint a, uint b) { return a > b ? a : b; }

// ---- kernel 0: E -> LINEAR f16 hi/lo (x2048) + embT + enorm + zeros ----------
__global__ __launch_bounds__(64) void vq_prep(const float* __restrict__ emb,
                                              ushort* __restrict__ embPh,
                                              ushort* __restrict__ embPl,
                                              float* __restrict__ embT,
                                              float* __restrict__ enorm,
                                              uint* __restrict__ counts,
                                              uint* __restrict__ flag_count) {
  const int k = blockIdx.x * 64 + threadIdx.x;
  const float4* __restrict__ ep4 = (const float4*)(emb + k * kD);
  float ev[kD];
  uint uh[32], ul[32];
  float s = 0.f;
#pragma unroll
  for (int j = 0; j < kD / 4; ++j) {
    const float4 v = ep4[j];
    ev[4 * j] = v.x; ev[4 * j + 1] = v.y; ev[4 * j + 2] = v.z; ev[4 * j + 3] = v.w;
    s = fmaf(v.x, v.x, s); s = fmaf(v.y, v.y, s);
    s = fmaf(v.z, v.z, s); s = fmaf(v.w, v.w, s);
#pragma unroll
    for (int t = 0; t < 2; ++t) {
      const float e0 = ev[4 * j + 2 * t] * 2048.f;
      const float e1 = ev[4 * j + 2 * t + 1] * 2048.f;
      const _Float16 h0 = (_Float16)e0, h1 = (_Float16)e1;
      const _Float16 l0 = (_Float16)(e0 - (float)h0);
      const _Float16 l1 = (_Float16)(e1 - (float)h1);
      uh[2 * j + t] = (uint)hb(h0) | ((uint)hb(h1) << 16);
      ul[2 * j + t] = (uint)hb(l0) | ((uint)hb(l1) << 16);
    }
  }
  // LINEAR store (direct per-lane reads in vq_assign — no swizzle)
  uint4* __restrict__ ph4 = (uint4*)embPh;
  uint4* __restrict__ pl4 = (uint4*)embPl;
#pragma unroll
  for (int cc = 0; cc < 8; ++cc) {
    const int dst = k * 8 + cc;
    ph4[dst] = uint4{uh[4 * cc], uh[4 * cc + 1], uh[4 * cc + 2], uh[4 * cc + 3]};
    pl4[dst] = uint4{ul[4 * cc], ul[4 * cc + 1], ul[4 * cc + 2], ul[4 * cc + 3]};
  }
#pragma unroll
  for (int c = 0; c < kD; ++c) embT[c * kK + k] = ev[c];
  enorm[k] = s;
  counts[k] = 0u;
  if (k == 0) *flag_count = 0u;
}

// ---- kernel 1: register-direct MFMA argmin + flags + hist + loss + QW --------
// Block 256 thr = 4 waves, 128 pts.  Wave w: pts [w*32..+32) x all 512 codes.
// C/D: col=lane&15 (code), row=(lane>>4)*4+reg (point).
__global__ __launch_bounds__(256, 4) void vq_assign(
    const float* __restrict__ in, const ushort* __restrict__ embPh,
    const ushort* __restrict__ embPl, const float* __restrict__ embT,
    const float* __restrict__ enorm, float* __restrict__ idx_out,
    float* __restrict__ outq, uint* __restrict__ counts,
    float* __restrict__ partial, uint* __restrict__ flag_count,
    uint* __restrict__ flags, uint flag_cap) {
  __shared__ __align__(16) char lds[32768];
  char* __restrict__ xbh = lds;                    // 16 KiB X hi (f16 of -2x)
  char* __restrict__ xbl = lds + 16384;            // 16 KiB X lo
  // aliased AFTER the A-hoist (X dead):
  uint* __restrict__ hist = (uint*)lds;            // [512]
  uint* __restrict__ fidx = (uint*)(lds + 2048);   // [128]

  const int tid = threadIdx.x;
  const int lane = tid & 63;
  const int w = __builtin_amdgcn_readfirstlane(tid >> 6);  // wave 0..3
  const int c = lane & 15;   // tile col (code)
  const int g = lane >> 4;   // k-chunk group 0..3

  const int blk = blockIdx.x;
  const int bb = blk >> 5;                  // batch
  const int hw0 = (blk & 31) << 7;          // 128 contiguous hw points
  const float* __restrict__ xp = in + (size_t)bb * kCHW + hw0;

  // ---- stage X: wave w converts dims [w*16..+16) for pts {lane, lane+64};
  // xnorm accumulated in-register (no per-point storage needed: loss splits
  // as Sum(s) + Sum(xnorm)).
  float xn = 0.f;
#pragma unroll
  for (int pp = 0; pp < 2; ++pp) {
    const int p = pp * 64 + lane;
    uint uh[8], ul[8];
#pragma unroll
    for (int j = 0; j < 8; ++j) {
      const float f0 = xp[(size_t)(w * 16 + 2 * j) * kHW + p];
      const float f1 = xp[(size_t)(w * 16 + 2 * j + 1) * kHW + p];
      xn = fmaf(f0, f0, xn);
      xn = fmaf(f1, f1, xn);
      const float m0 = -2.f * f0, m1f = -2.f * f1;
      const _Float16 h0 = (_Float16)m0, h1 = (_Float16)m1f;
      const _Float16 l0 = (_Float16)(m0 - (float)h0);
      const _Float16 l1 = (_Float16)(m1f - (float)h1);
      uh[j] = (uint)hb(h0) | ((uint)hb(h1) << 16);
      ul[j] = (uint)hb(l0) | ((uint)hb(l1) << 16);
    }
    const int swz = (p & 7) << 4;
    const int o0 = (p * 128 + w * 32) ^ swz;
    const int o1 = (p * 128 + w * 32 + 16) ^ swz;
    *(uint4*)(xbh + o0) = uint4{uh[0], uh[1], uh[2], uh[3]};
    *(uint4*)(xbh + o1) = uint4{uh[4], uh[5], uh[6], uh[7]};
    *(uint4*)(xbl + o0) = uint4{ul[0], ul[1], ul[2], ul[3]};
    *(uint4*)(xbl + o1) = uint4{ul[4], ul[5], ul[6], ul[7]};
  }
  // wave xnorm partial (covers dims [w*16..+16) of all 128 pts)
  {
    float xw = xn;
#pragma unroll
    for (int off = 32; off > 0; off >>= 1) xw += __shfl_down(xw, off, 64);
    if (lane == 0) partial[blk * 8 + 4 + w] = xw;
  }
  __syncthreads();   // X staged

  // ---- hoist A-fragments (hi+lo): 8 f16x8 = 32 VGPR, loop-invariant ----
  f16x8 ah[2][2], al[2][2];
#pragma unroll
  for (int rt = 0; rt < 2; ++rt)
#pragma unroll
    for (int s = 0; s < 2; ++s) {
      const int row = w * 32 + rt * 16 + c;
      const int off = (row * 128 + g * 16 + s * 64) ^ ((row & 7) << 4);
      ah[rt][s] = *(const f16x8*)(xbh + off);
      al[rt][s] = *(const f16x8*)(xbl + off);
    }
  __syncthreads();   // X dead -> aliases OK
  hist[tid] = 0u;
  hist[tid + 256] = 0u;
  __syncthreads();   // hist zeroed before any wave's post-loop atomics

  uint m1[8], m2[8];
#pragma unroll
  for (int i = 0; i < 8; ++i) { m1[i] = 0xFFFFFFFFu; m2[i] = 0xFFFFFFFFu; }

  // ---- hot loop: 32 steps x 16 codes, ZERO barriers / ZERO LDS.  B-frags
  // stream from L2 (coalesced 16B/lane); compiler pipelines across unroll.
  const char* __restrict__ phc = (const char*)embPh + c * 128 + g * 16;
  const char* __restrict__ plc = (const char*)embPl + c * 128 + g * 16;
#pragma unroll 4
  for (int st = 0; st < 32; ++st) {
    const int eoff = st * 2048;               // 16 codes * 128 B
    const f16x8 bh0 = *(const f16x8*)(phc + eoff);
    const f16x8 bh1 = *(const f16x8*)(phc + eoff + 64);
    const f16x8 bl0 = *(const f16x8*)(plc + eoff);
    const f16x8 bl1 = *(const f16x8*)(plc + eoff + 64);
    const float en = (enorm[st * 16 + c] + 256.f) * 2048.f;
    const uint kor = (uint)(st * 16 + c);
#pragma unroll
    for (int rt = 0; rt < 2; ++rt) {
      f32x4 acc = {en, en, en, en};
      acc = __builtin_amdgcn_mfma_f32_16x16x32_f16(ah[rt][0], bh0, acc, 0, 0, 0);
      acc = __builtin_amdgcn_mfma_f32_16x16x32_f16(ah[rt][1], bh1, acc, 0, 0, 0);
      acc = __builtin_amdgcn_mfma_f32_16x16x32_f16(ah[rt][0], bl0, acc, 0, 0, 0);
      acc = __builtin_amdgcn_mfma_f32_16x16x32_f16(ah[rt][1], bl1, acc, 0, 0, 0);
      acc = __builtin_amdgcn_mfma_f32_16x16x32_f16(al[rt][0], bh0, acc, 0, 0, 0);
      acc = __builtin_amdgcn_mfma_f32_16x16x32_f16(al[rt][1], bh1, acc, 0, 0, 0);
#pragma unroll
      for (int r = 0; r < 4; ++r) {
        const uint u = ((uint)acc[r] << 9) | kor;   // fixed-point pack
        const int i = rt * 4 + r;
        const uint t = umax(m1[i], u);
        m1[i] = umin(m1[i], u);
        m2[i] = umin(m2[i], t);
      }
    }
  }

  // ---- cross-col butterfly (16 c-lanes per point); all in-wave ----
#pragma unroll
  for (int i = 0; i < 8; ++i) {
    uint a1 = m1[i], a2 = m2[i];
#pragma unroll
    for (int off = 1; off < 16; off <<= 1) {
      const uint o1 = __shfl_xor(a1, off, 64);
      const uint o2 = __shfl_xor(a2, off, 64);
      const uint t = umax(a1, o1);
      a1 = umin(a1, o1);
      a2 = umin(umin(a2, o2), t);
    }
    m1[i] = a1; m2[i] = a2;
  }

  // ---- c==0 lanes own final results for 8 pts each: idx/flags/hist/loss ----
  float d2 = 0.f;
  if (c == 0) {
#pragma unroll
    for (int i = 0; i < 8; ++i) {
      const int rt = i >> 2, r = i & 3;
      const int p = w * 32 + rt * 16 + g * 4 + r;
      const int n = blk * 128 + p;
      const uint bidx = m1[i] & 511u;
      fidx[p] = bidx;
      idx_out[n] = (float)bidx;
      if (((m2[i] >> 9) - (m1[i] >> 9)) < kGapFP) {   // near-tie -> recheck
        const uint slot = atomicAdd(flag_count, 1u);
        if (slot < flag_cap) flags[slot] = (uint)n;
      }
      atomicAdd(&hist[bidx], 1u);
      d2 += fmaf((float)(m1[i] >> 9), 1.f / 2048.f, -256.f);
    }
  }
#pragma unroll
  for (int off = 32; off > 0; off >>= 1) d2 += __shfl_down(d2, off, 64);
  if (lane == 0) partial[blk * 8 + w] = d2;
  __syncthreads();   // fidx + hist complete

  if (hist[tid]) atomicAdd(&counts[tid], hist[tid]);
  if (hist[tid + 256]) atomicAdd(&counts[tid + 256], hist[tid + 256]);

  // ---- fused quantized write: 128 pts x 64 c, coalesced NCHW stores ----
  {
    const int ch = tid >> 2;          // channel 0..63
    const int wq = tid & 3;           // 32-pt chunk 0..3
    const float* __restrict__ tr = embT + ch * kK;
    float* __restrict__ oq = outq + (size_t)bb * kCHW + (size_t)ch * kHW + hw0 + wq * 32;
#pragma unroll
    for (int i = 0; i < 8; ++i) {
      const int p0 = wq * 32 + i * 4;
      float4 v;
      v.x = tr[fidx[p0 + 0]];
      v.y = tr[fidx[p0 + 1]];
      v.z = tr[fidx[p0 + 2]];
      v.w = tr[fidx[p0 + 3]];
      *(float4*)(oq + i * 4) = v;
    }
  }
}

// ---- kernel 1b: exact f64 re-argmin, ONE WAVE per flagged point; patches
// both idx_out and the quantized output row.
__global__ __launch_bounds__(256) void vq_refine(const float* __restrict__ in,
                                                 const float* __restrict__ emb,
                                                 const uint* __restrict__ flag_count,
                                                 const uint* __restrict__ flags,
                                                 uint flag_cap,
                                                 float* __restrict__ idx_out,
                                                 float* __restrict__ outq) {
  uint cnt = *flag_count;
  if (cnt > flag_cap) cnt = flag_cap;
  const int lane = threadIdx.x & 63;
  const uint wave_id = blockIdx.x * 4u + (threadIdx.x >> 6);
  const uint wave_stride = gridDim.x * 4u;

  for (uint i = wave_id; i < cnt; i += wave_stride) {
    const int n = (int)flags[i];          // wave-uniform
    const int b = n >> 12;
    const int hw = n & 4095;
    const float* __restrict__ xp = in + (size_t)b * kCHW + hw;

    float xr[kD];
#pragma unroll
    for (int d = 0; d < kD; ++d) xr[d] = xp[(size_t)d * kHW];

    double best = 1e300;
    int bidx = 0;
#pragma unroll 1
    for (int kk = 0; kk < 8; ++kk) {
      const int k = lane * 8 + kk;
      const float4* __restrict__ ep4 = (const float4*)(emb + k * kD);
      double s0 = 0.0, s1 = 0.0;
#pragma unroll
      for (int j = 0; j < kD / 4; ++j) {
        const float4 e = ep4[j];
        const double d0 = (double)xr[4 * j + 0] - (double)e.x;
        const double d1 = (double)xr[4 * j + 1] - (double)e.y;
        const double d2 = (double)xr[4 * j + 2] - (double)e.z;
        const double d3 = (double)xr[4 * j + 3] - (double)e.w;
        s0 = fma(d0, d0, s0);
        s1 = fma(d1, d1, s1);
        s0 = fma(d2, d2, s0);
        s1 = fma(d3, d3, s1);
      }
      const double s = s0 + s1;
      if (s < best) { best = s; bidx = k; }  // strict < == first-min in-lane
    }
#pragma unroll
    for (int off = 32; off > 0; off >>= 1) {
      const double ob = __shfl_xor(best, off, 64);
      const int oi = __shfl_xor(bidx, off, 64);
      if (ob < best || (ob == best && oi < bidx)) { best = ob; bidx = oi; }
    }
    if (lane == 0) idx_out[n] = (float)bidx;
    // patch quantized row: lane = channel
    outq[(size_t)b * kCHW + (size_t)lane * kHW + hw] = emb[bidx * kD + lane];
  }
}

// ---- kernel 2: scalars (loss, perplexity, usage) -----------------------------
__global__ __launch_bounds__(512) void vq_finalize(const float* __restrict__ weight,
                                                   const uint* __restrict__ counts,
                                                   const float* __restrict__ partial,
                                                   float* __restrict__ out_scalars) {
  __shared__ float red[512];
  const int t = threadIdx.x;

  const float avg = (float)counts[t] / (float)kN;
  red[t] = avg * logf(avg + 1e-10f);
  __syncthreads();
#pragma unroll
  for (int off = 256; off > 0; off >>= 1) {
    if (t < off) red[t] += red[t + off];
    __syncthreads();
  }
  const float perp = expf(-red[0]);
  __syncthreads();

  // 8192 loss partials (1024 blocks x 8 slots), fixed order -> deterministic
  {
    float acc = 0.f;
#pragma unroll
    for (int j = 0; j < 16; ++j) acc += partial[t + 512 * j];
    red[t] = acc;
  }
  __syncthreads();
#pragma unroll
  for (int off = 256; off > 0; off >>= 1) {
    if (t < off) red[t] += red[t + off];
    __syncthreads();
  }
  const float loss = red[0] / (float)((long long)kN * (long long)kD);
  __syncthreads();

  red[t] = (weight[t] >= 0.01f) ? 1.f : 0.f;
  __syncthreads();
#pragma unroll
  for (int off = 256; off > 0; off >>= 1) {
    if (t < off) red[t] += red[t + off];
    __syncthreads();
  }
  if (t == 0) {
    out_scalars[0] = loss;
    out_scalars[1] = perp;
    out_scalars[2] = red[0];
  }
}

extern "C" void kernel_launch(void* const* d_in, const int* in_sizes, int n_in,
                              void* d_out, int out_size, void* d_ws, size_t ws_size,
                              hipStream_t stream) {
  const float* in = (const float*)d_in[0];
  const float* emb = (const float*)d_in[1];
  const float* weight = (const float*)d_in[2];
  float* out = (float*)d_out;

  // workspace layout (4 B units)
  float* ws_f = (float*)d_ws;
  uint* ws_u = (uint*)d_ws;
  ushort* embPh = (ushort*)d_ws;            // 64 KiB  -> u32 [0, 16384)
  ushort* embPl = embPh + kK * kD;          // 64 KiB  -> u32 [16384, 32768)
  float* embT = ws_f + 32768;               // 128 KiB -> [32768, 65536)
  float* enorm = ws_f + 65536;              // [512]
  uint* counts = ws_u + 66048;              // [512]
  float* partial = ws_f + 66560;            // [8192]
  uint* flag_count = ws_u + 74752;          // [1]
  uint* flags = ws_u + 74753;               // [flag_cap]
  const size_t ws_elems = ws_size / 4;
  const uint flag_cap =
      (ws_elems > 74753)
          ? (uint)((ws_elems - 74753 < (size_t)kN) ? ws_elems - 74753 : (size_t)kN)
          : 0u;

  float* outq = out;                    // [8388608]
  float* out_scalars = out + kQElems;   // [3]
  float* idx_out = out + kQElems + 3;   // [131072]

  vq_prep<<<8, 64, 0, stream>>>(emb, embPh, embPl, embT, enorm, counts, flag_count);
  vq_assign<<<kN / 128, 256, 0, stream>>>(in, embPh, embPl, embT, enorm, idx_out,
                                          outq, counts, partial, flag_count, flags,
                                          flag_cap);
  vq_refine<<<256, 256, 0, stream>>>(in, emb, flag_count, flags, flag_cap,
                                     idx_out, outq);
  vq_finalize<<<1, 512, 0, stream>>>(weight, counts, partial, out_scalars);
}

// Round 18
// 91.370 us; speedup vs baseline: 1.3485x; 1.3485x over previous
//
#include <hip/hip_runtime.h>

// VectorQuantizer on MI355X (gfx950) — async-pipelined MFMA argmin (counted
// vmcnt, raw s_barrier) with fused quantized write; f64 refine patches ties.
// R18 = r15 (best measured: 90.2 us total) + SPLIT ACCUMULATORS: the 6-MFMA
// serial accumulation chain per rt-tile becomes two 3-MFMA chains summed at
// the end — halves the dependency latency, doubles per-wave ILP (4->8 chains).
//
// Distance core: s = ||e||^2 - 2 x.e.  E pre-scaled by 2048, f16 hi/lo split,
// PRE-SWIZZLED in ws (per-lane gld16 source, linear LDS dest).  X = f16 hi/lo
// of (-2x).  3-term MFMA (xh.eh + xh.el + xl.eh).  C-init = (||e||^2+256)*2048;
// packed key ((uint)acc << 9) | idx -> u32-min argmin, first-min tie-break.
// Near-ties (gap < 21/2048) re-solved in f64 by vq_refine (patches idx AND
// quantized rows).  Loss/hist pre-refine (error << tolerances).

typedef __attribute__((ext_vector_type(8))) _Float16 f16x8;
typedef __attribute__((ext_vector_type(4))) float f32x4;
typedef unsigned int uint;
typedef unsigned short ushort;

namespace {
constexpr int kC = 64, kH = 64, kW = 64;
constexpr int kK = 512, kD = 64;
constexpr int kHW = kH * kW;                  // 4096
constexpr int kCHW = kC * kHW;                // 262144
constexpr int kN = 32 * kHW;                  // 131072
constexpr int kQElems = 32 * kC * kHW;        // 8388608
constexpr uint kGapFP = 21u;                  // 0.0103 in 1/2048 units
}

__device__ __forceinline__ ushort hb(_Float16 h) { return __builtin_bit_cast(ushort, h); }
__device__ __forceinline__ uint umin(uint a, uint b) { return a < b ? a : b; }
__device__ __forceinline__ uint umax(uint a, uint b) { return a > b ? a : b; }

__device__ __forceinline__ void gld16(const void* g, void* l) {
  __builtin_amdgcn_global_load_lds(
      (const __attribute__((address_space(1))) uint*)g,
      (__attribute__((address_space(3))) uint*)l, 16, 0, 0);
}

// ---- kernel 0: E -> pre-swizzled f16 hi/lo (x2048) + embT + enorm + zeros ----
__global__ __launch_bounds__(64) void vq_prep(const float* __restrict__ emb,
                                              ushort* __restrict__ embPh,
                                              ushort* __restrict__ embPl,
                                              float* __restrict__ embT,
                                              float* __restrict__ enorm,
                                              uint* __restrict__ counts,
                                              uint* __restrict__ flag_count) {
  const int k = blockIdx.x * 64 + threadIdx.x;
  const float4* __restrict__ ep4 = (const float4*)(emb + k * kD);
  float ev[kD];
  uint uh[32], ul[32];
  float s = 0.f;
#pragma unroll
  for (int j = 0; j < kD / 4; ++j) {
    const float4 v = ep4[j];
    ev[4 * j] = v.x; ev[4 * j + 1] = v.y; ev[4 * j + 2] = v.z; ev[4 * j + 3] = v.w;
    s = fmaf(v.x, v.x, s); s = fmaf(v.y, v.y, s);
    s = fmaf(v.z, v.z, s); s = fmaf(v.w, v.w, s);
#pragma unroll
    for (int t = 0; t < 2; ++t) {
      const float e0 = ev[4 * j + 2 * t] * 2048.f;
      const float e1 = ev[4 * j + 2 * t + 1] * 2048.f;
      const _Float16 h0 = (_Float16)e0, h1 = (_Float16)e1;
      const _Float16 l0 = (_Float16)(e0 - (float)h0);
      const _Float16 l1 = (_Float16)(e1 - (float)h1);
      uh[2 * j + t] = (uint)hb(h0) | ((uint)hb(h1) << 16);
      ul[2 * j + t] = (uint)hb(l0) | ((uint)hb(l1) << 16);
    }
  }
  // pre-swizzled store: embP[k*128B + (cc^(k&7))*16B] = linear chunk cc
  uint4* __restrict__ ph4 = (uint4*)embPh;
  uint4* __restrict__ pl4 = (uint4*)embPl;
#pragma unroll
  for (int cc = 0; cc < 8; ++cc) {
    const int dst = k * 8 + (cc ^ (k & 7));
    ph4[dst] = uint4{uh[4 * cc], uh[4 * cc + 1], uh[4 * cc + 2], uh[4 * cc + 3]};
    pl4[dst] = uint4{ul[4 * cc], ul[4 * cc + 1], ul[4 * cc + 2], ul[4 * cc + 3]};
  }
#pragma unroll
  for (int c = 0; c < kD; ++c) embT[c * kK + k] = ev[c];
  enorm[k] = s;
  counts[k] = 0u;
  if (k == 0) *flag_count = 0u;
}

// ---- kernel 1: MFMA argmin + flags + hist + loss + QUANTIZED WRITE -----------
// Block = 512 thr = 8 waves = 128 points x all 512 codes in 8 dbuf-staged
// 64-code chunks.  Wave (ph=wv>>2, cs=wv&3).  Wave stages ITS OWN 16 rows.
// C/D: col=lane&15 (code), row=(lane>>4)*4+reg (point).
__global__ __launch_bounds__(512, 4) void vq_assign(
    const float* __restrict__ in, const ushort* __restrict__ embPh,
    const ushort* __restrict__ embPl, const float* __restrict__ embT,
    const float* __restrict__ enorm, float* __restrict__ idx_out,
    float* __restrict__ outq, uint* __restrict__ counts,
    float* __restrict__ partial, uint* __restrict__ flag_count,
    uint* __restrict__ flags, uint flag_cap) {
  __shared__ __align__(16) ushort xbh[128 * 64];  // 16 KiB X hi (f16 of -2x)
  __shared__ __align__(16) ushort xbl[128 * 64];  // 16 KiB X lo
  __shared__ __align__(16) ushort ebh[2][4096];   // 16 KiB E hi dbuf (64 codes)
  __shared__ __align__(16) ushort ebl[2][4096];   // 16 KiB E lo dbuf
  __shared__ uint mm1[4][128], mm2[4][128];       // 4 KiB merge
  __shared__ float xnp[4][128];                   // 2 KiB xnorm partials
  __shared__ uint hist[512];                      // 2 KiB block histogram
  __shared__ uint fidx[128];                      // pre-refine indices

  const int tid = threadIdx.x;
  const int lane = tid & 63;
  const int wv = __builtin_amdgcn_readfirstlane(tid >> 6);
  const int ph = wv >> 2;    // point-half
  const int cs = wv & 3;     // code-sub (16 codes per 64-code chunk)
  const int c = lane & 15;   // tile col (code)
  const int g = lane >> 4;   // k-chunk group 0..3

  const int blk = blockIdx.x;
  const int bb = blk >> 5;                  // batch
  const int hw0 = (blk & 31) << 7;          // 128 contiguous hw points
  const float* __restrict__ xp = in + (size_t)bb * kCHW + hw0 + ph * 64;

  hist[tid] = 0u;

  // SELF-STAGE: wave (ph,cs) stages rows [cs*16, cs*16+16) of chunk st —
  // exactly the rows it reads.  ph-siblings duplicate identical bytes (benign).
  auto stageE = [&](int buf, int st) {
    const size_t src = (size_t)st * 8192 + cs * 2048;
    const int dst = cs * 2048;
#pragma unroll
    for (int i = 0; i < 2; ++i) {
      gld16((const char*)embPh + src + i * 1024 + lane * 16,
            (char*)&ebh[buf][0] + dst + i * 1024);
      gld16((const char*)embPl + src + i * 1024 + lane * 16,
            (char*)&ebl[buf][0] + dst + i * 1024);
    }
  };
  stageE(0, 0);   // prologue prefetch, flies under X staging

  // scaled+biased C-init per lane for the 8 chunks
  float en_pre[8];
#pragma unroll
  for (int st = 0; st < 8; ++st)
    en_pre[st] = (enorm[st * 64 + cs * 16 + c] + 256.f) * 2048.f;

  // ---- stage X (hi/lo of -2x) + xnorm partial over this wave's 16 dims ----
  {
    const int p = lane;
    uint uh[8], ul[8];
    float xn = 0.f;
#pragma unroll
    for (int j = 0; j < 8; ++j) {
      const float f0 = xp[(size_t)(cs * 16 + 2 * j) * kHW + p];
      const float f1 = xp[(size_t)(cs * 16 + 2 * j + 1) * kHW + p];
      xn = fmaf(f0, f0, xn);
      xn = fmaf(f1, f1, xn);
      const float m0 = -2.f * f0, m1f = -2.f * f1;
      const _Float16 h0 = (_Float16)m0, h1 = (_Float16)m1f;
      const _Float16 l0 = (_Float16)(m0 - (float)h0);
      const _Float16 l1 = (_Float16)(m1f - (float)h1);
      uh[j] = (uint)hb(h0) | ((uint)hb(h1) << 16);
      ul[j] = (uint)hb(l0) | ((uint)hb(l1) << 16);
    }
    const int row = ph * 64 + p;
    const int swz = (row & 7) << 4;
    const int o0 = (row * 128 + cs * 32) ^ swz;
    const int o1 = (row * 128 + cs * 32 + 16) ^ swz;
    *(uint4*)((char*)xbh + o0) = uint4{uh[0], uh[1], uh[2], uh[3]};
    *(uint4*)((char*)xbh + o1) = uint4{uh[4], uh[5], uh[6], uh[7]};
    *(uint4*)((char*)xbl + o0) = uint4{ul[0], ul[1], ul[2], ul[3]};
    *(uint4*)((char*)xbl + o1) = uint4{ul[4], ul[5], ul[6], ul[7]};
    xnp[cs][row] = xn;
  }
  __syncthreads();   // full drain ONCE: X staged + chunk 0 landed

  uint m1[16], m2[16];
#pragma unroll
  for (int i = 0; i < 16; ++i) { m1[i] = 0xFFFFFFFFu; m2[i] = 0xFFFFFFFFu; }

#pragma unroll
  for (int st = 0; st < 8; ++st) {
    if (st < 7) stageE((st & 1) ^ 1, st + 1);   // prefetch stays in flight

    // counted wait: my own chunk-st loads landed (4 newest = chunk st+1)
    if (st < 7) {
      asm volatile("s_waitcnt vmcnt(4)" ::: "memory");
    } else {
      asm volatile("s_waitcnt vmcnt(0)" ::: "memory");
    }
    __builtin_amdgcn_sched_barrier(0);

    // B-frags: this wave's 16-code slice of the chunk (self-staged)
    const int rowb = cs * 16 + c;
    const int swb = (rowb & 7) << 4;
    const int ob0 = (rowb * 128 + g * 16) ^ swb;
    const int ob1 = (rowb * 128 + g * 16 + 64) ^ swb;
    const int bsel = st & 1;
    const f16x8 bh0 = *(const f16x8*)((const char*)&ebh[bsel][0] + ob0);
    const f16x8 bh1 = *(const f16x8*)((const char*)&ebh[bsel][0] + ob1);
    const f16x8 bl0 = *(const f16x8*)((const char*)&ebl[bsel][0] + ob0);
    const f16x8 bl1 = *(const f16x8*)((const char*)&ebl[bsel][0] + ob1);
    const float en = en_pre[st];
    const uint kor = (uint)(st * 64 + cs * 16 + c);
    __builtin_amdgcn_s_setprio(1);
#pragma unroll
    for (int rt = 0; rt < 4; ++rt) {
      f16x8 ah[2], al[2];
#pragma unroll
      for (int s = 0; s < 2; ++s) {
        const int row = ph * 64 + rt * 16 + c;
        const int off = (row * 128 + g * 16 + s * 64) ^ ((row & 7) << 4);
        ah[s] = *(const f16x8*)((const char*)xbh + off);
        al[s] = *(const f16x8*)((const char*)xbl + off);
      }
      // SPLIT ACCUMULATORS: two independent 3-MFMA chains (was one 6-chain)
      f32x4 acc0 = {en, en, en, en};
      f32x4 acc1 = {0.f, 0.f, 0.f, 0.f};
      acc0 = __builtin_amdgcn_mfma_f32_16x16x32_f16(ah[0], bh0, acc0, 0, 0, 0);
      acc1 = __builtin_amdgcn_mfma_f32_16x16x32_f16(ah[1], bh1, acc1, 0, 0, 0);
      acc0 = __builtin_amdgcn_mfma_f32_16x16x32_f16(ah[0], bl0, acc0, 0, 0, 0);
      acc1 = __builtin_amdgcn_mfma_f32_16x16x32_f16(ah[1], bl1, acc1, 0, 0, 0);
      acc0 = __builtin_amdgcn_mfma_f32_16x16x32_f16(al[0], bh0, acc0, 0, 0, 0);
      acc1 = __builtin_amdgcn_mfma_f32_16x16x32_f16(al[1], bh1, acc1, 0, 0, 0);
#pragma unroll
      for (int r = 0; r < 4; ++r) {
        const uint u = ((uint)(acc0[r] + acc1[r]) << 9) | kor;  // fixed-point
        const int i = rt * 4 + r;
        const uint t = umax(m1[i], u);
        m1[i] = umin(m1[i], u);
        m2[i] = umin(m2[i], t);
      }
    }
    __builtin_amdgcn_s_setprio(0);

    // step-end rendezvous WITHOUT vmcnt drain (prefetch stays in flight)
    asm volatile("s_waitcnt lgkmcnt(0)" ::: "memory");
    __builtin_amdgcn_sched_barrier(0);
    __builtin_amdgcn_s_barrier();
  }

  // ---- cross-col butterfly (16 c-lanes per point) ----
#pragma unroll
  for (int i = 0; i < 16; ++i) {
    uint a1 = m1[i], a2 = m2[i];
#pragma unroll
    for (int off = 1; off < 16; off <<= 1) {
      const uint o1 = __shfl_xor(a1, off, 64);
      const uint o2 = __shfl_xor(a2, off, 64);
      const uint t = umax(a1, o1);
      a1 = umin(a1, o1);
      a2 = umin(umin(a2, o2), t);
    }
    m1[i] = a1; m2[i] = a2;
  }

  if (c == 0) {
#pragma unroll
    for (int i = 0; i < 16; ++i) {
      const int p = ph * 64 + (i >> 2) * 16 + g * 4 + (i & 3);
      mm1[cs][p] = m1[i];
      mm2[cs][p] = m2[i];
    }
  }
  __syncthreads();

  // ---- cross-wave merge + idx/flags/hist/loss ----
  if (tid < 128) {
    uint a1 = mm1[0][tid], a2 = mm2[0][tid];
#pragma unroll
    for (int s = 1; s < 4; ++s) {
      const uint u1 = mm1[s][tid], u2 = mm2[s][tid];
      const uint t = umax(a1, u1);
      a1 = umin(a1, u1);
      a2 = umin(umin(a2, u2), t);
    }
    const uint bidx = a1 & 511u;
    fidx[tid] = bidx;
    idx_out[blk * 128 + tid] = (float)bidx;
    if (((a2 >> 9) - (a1 >> 9)) < kGapFP) {   // near-tie -> exact recheck
      const uint slot = atomicAdd(flag_count, 1u);
      if (slot < flag_cap) flags[slot] = (uint)(blk * 128 + tid);
    }
    atomicAdd(&hist[bidx], 1u);

    const float xnorm = (xnp[0][tid] + xnp[1][tid]) + (xnp[2][tid] + xnp[3][tid]);
    float d2 = fmaf((float)(a1 >> 9), 1.f / 2048.f, -256.f) + xnorm;
#pragma unroll
    for (int off = 32; off > 0; off >>= 1) d2 += __shfl_down(d2, off, 64);
    if ((tid & 63) == 0) partial[blk * 2 + (tid >> 6)] = d2;
  }
  __syncthreads();
  if (hist[tid]) atomicAdd(&counts[tid], hist[tid]);

  // ---- fused quantized write: 128 pts x 64 c, coalesced NCHW stores ----
  {
    const int ch = tid >> 3;          // channel 0..63
    const int wq = tid & 7;           // 16-pt chunk 0..7
    const float* __restrict__ tr = embT + ch * kK;
    float* __restrict__ oq = outq + (size_t)bb * kCHW + (size_t)ch * kHW + hw0 + wq * 16;
#pragma unroll
    for (int i = 0; i < 4; ++i) {
      const int p0 = wq * 16 + i * 4;
      float4 v;
      v.x = tr[fidx[p0 + 0]];
      v.y = tr[fidx[p0 + 1]];
      v.z = tr[fidx[p0 + 2]];
      v.w = tr[fidx[p0 + 3]];
      *(float4*)(oq + i * 4) = v;
    }
  }
}

// ---- kernel 1b: exact f64 re-argmin, ONE WAVE per flagged point; patches
// both idx_out and the quantized output row.
__global__ __launch_bounds__(256) void vq_refine(const float* __restrict__ in,
                                                 const float* __restrict__ emb,
                                                 const uint* __restrict__ flag_count,
                                                 const uint* __restrict__ flags,
                                                 uint flag_cap,
                                                 float* __restrict__ idx_out,
                                                 float* __restrict__ outq) {
  uint cnt = *flag_count;
  if (cnt > flag_cap) cnt = flag_cap;
  const int lane = threadIdx.x & 63;
  const uint wave_id = blockIdx.x * 4u + (threadIdx.x >> 6);
  const uint wave_stride = gridDim.x * 4u;

  for (uint i = wave_id; i < cnt; i += wave_stride) {
    const int n = (int)flags[i];          // wave-uniform
    const int b = n >> 12;
    const int hw = n & 4095;
    const float* __restrict__ xp = in + (size_t)b * kCHW + hw;

    float xr[kD];
#pragma unroll
    for (int d = 0; d < kD; ++d) xr[d] = xp[(size_t)d * kHW];

    double best = 1e300;
    int bidx = 0;
#pragma unroll 1
    for (int kk = 0; kk < 8; ++kk) {
      const int k = lane * 8 + kk;
      const float4* __restrict__ ep4 = (const float4*)(emb + k * kD);
      double s0 = 0.0, s1 = 0.0;
#pragma unroll
      for (int j = 0; j < kD / 4; ++j) {
        const float4 e = ep4[j];
        const double d0 = (double)xr[4 * j + 0] - (double)e.x;
        const double d1 = (double)xr[4 * j + 1] - (double)e.y;
        const double d2 = (double)xr[4 * j + 2] - (double)e.z;
        const double d3 = (double)xr[4 * j + 3] - (double)e.w;
        s0 = fma(d0, d0, s0);
        s1 = fma(d1, d1, s1);
        s0 = fma(d2, d2, s0);
        s1 = fma(d3, d3, s1);
      }
      const double s = s0 + s1;
      if (s < best) { best = s; bidx = k; }  // strict < == first-min in-lane
    }
#pragma unroll
    for (int off = 32; off > 0; off >>= 1) {
      const double ob = __shfl_xor(best, off, 64);
      const int oi = __shfl_xor(bidx, off, 64);
      if (ob < best || (ob == best && oi < bidx)) { best = ob; bidx = oi; }
    }
    if (lane == 0) idx_out[n] = (float)bidx;
    // patch quantized row: lane = channel
    outq[(size_t)b * kCHW + (size_t)lane * kHW + hw] = emb[bidx * kD + lane];
  }
}

// ---- kernel 2: scalars (loss, perplexity, usage) -----------------------------
__global__ __launch_bounds__(512) void vq_finalize(const float* __restrict__ weight,
                                                   const uint* __restrict__ counts,
                                                   const float* __restrict__ partial,
                                                   float* __restrict__ out_scalars) {
  __shared__ float red[512];
  const int t = threadIdx.x;

  const float avg = (float)counts[t] / (float)kN;
  red[t] = avg * logf(avg + 1e-10f);
  __syncthreads();
#pragma unroll
  for (int off = 256; off > 0; off >>= 1) {
    if (t < off) red[t] += red[t + off];
    __syncthreads();
  }
  const float perp = expf(-red[0]);
  __syncthreads();

  // 2048 loss partials, fixed order -> deterministic
  red[t] = (partial[t] + partial[t + 512]) + (partial[t + 1024] + partial[t + 1536]);
  __syncthreads();
#pragma unroll
  for (int off = 256; off > 0; off >>= 1) {
    if (t < off) red[t] += red[t + off];
    __syncthreads();
  }
  const float loss = red[0] / (float)((long long)kN * (long long)kD);
  __syncthreads();

  red[t] = (weight[t] >= 0.01f) ? 1.f : 0.f;
  __syncthreads();
#pragma unroll
  for (int off = 256; off > 0; off >>= 1) {
    if (t < off) red[t] += red[t + off];
    __syncthreads();
  }
  if (t == 0) {
    out_scalars[0] = loss;
    out_scalars[1] = perp;
    out_scalars[2] = red[0];
  }
}

extern "C" void kernel_launch(void* const* d_in, const int* in_sizes, int n_in,
                              void* d_out, int out_size, void* d_ws, size_t ws_size,
                              hipStream_t stream) {
  const float* in = (const float*)d_in[0];
  const float* emb = (const float*)d_in[1];
  const float* weight = (const float*)d_in[2];
  float* out = (float*)d_out;

  // workspace layout (4 B units)
  float* ws_f = (float*)d_ws;
  uint* ws_u = (uint*)d_ws;
  ushort* embPh = (ushort*)d_ws;            // 64 KiB  -> u32 [0, 16384)
  ushort* embPl = embPh + kK * kD;          // 64 KiB  -> u32 [16384, 32768)
  float* embT = ws_f + 32768;               // 128 KiB -> [32768, 65536)
  float* enorm = ws_f + 65536;              // [512]
  uint* counts = ws_u + 66048;              // [512]
  float* partial = ws_f + 66560;            // [2048]
  uint* flag_count = ws_u + 68608;          // [1]
  uint* flags = ws_u + 68609;               // [flag_cap]
  const size_t ws_elems = ws_size / 4;
  const uint flag_cap =
      (ws_elems > 68609)
          ? (uint)((ws_elems - 68609 < (size_t)kN) ? ws_elems - 68609 : (size_t)kN)
          : 0u;

  float* outq = out;                    // [8388608]
  float* out_scalars = out + kQElems;   // [3]
  float* idx_out = out + kQElems + 3;   // [131072]

  vq_prep<<<8, 64, 0, stream>>>(emb, embPh, embPl, embT, enorm, counts, flag_count);
  vq_assign<<<kN / 128, 512, 0, stream>>>(in, embPh, embPl, embT, enorm, idx_out,
                                          outq, counts, partial, flag_count, flags,
                                          flag_cap);
  vq_refine<<<256, 256, 0, stream>>>(in, emb, flag_count, flags, flag_cap,
                                     idx_out, outq);
  vq_finalize<<<1, 512, 0, stream>>>(weight, counts, partial, out_scalars);
}

// Round 20
// 87.845 us; speedup vs baseline: 1.4026x; 1.0401x over previous
//
#include <hip/hip_runtime.h>

// VectorQuantizer on MI355X (gfx950) — async-pipelined MFMA argmin (counted
// vmcnt, raw s_barrier) with fused quantized write; f64 refine patches ties.
// R20 = r19 with the dbuf stride bug fixed: each 64-code chunk is 8192 B, so
// ebh/ebl are [2][8192 B] and buf stride is 8192 (r19 used 4096 -> buffers
// overlapped and ebh-odd staging clobbered ebl-even reads; refine masked it
// except pre-refine perplexity).  Epilogue = LDS-transpose quantized write:
// coalesced e-row fetches into XOR-swizzled LDS, NCHW-coalesced stores
// (replaces 32 random-gather instrs/thread that serialized the TA pipe).
//
// Distance core: s = ||e||^2 - 2 x.e.  E pre-scaled by 2048, f16 hi/lo split,
// PRE-SWIZZLED in ws (per-lane gld16 source, linear LDS dest).  X = f16 hi/lo
// of (-2x).  3-term MFMA (xh.eh + xh.el + xl.eh), split accumulators.
// C-init = (||e||^2+256)*2048; packed key ((uint)acc << 9) | idx -> u32-min
// argmin, first-min tie-break.  Near-ties (gap < 21/2048) re-solved in f64 by
// vq_refine (patches idx AND quantized rows).  Loss/hist pre-refine.

typedef __attribute__((ext_vector_type(8))) _Float16 f16x8;
typedef __attribute__((ext_vector_type(4))) float f32x4;
typedef unsigned int uint;
typedef unsigned short ushort;

namespace {
constexpr int kC = 64, kH = 64, kW = 64;
constexpr int kK = 512, kD = 64;
constexpr int kHW = kH * kW;                  // 4096
constexpr int kCHW = kC * kHW;                // 262144
constexpr int kN = 32 * kHW;                  // 131072
constexpr int kQElems = 32 * kC * kHW;        // 8388608
constexpr uint kGapFP = 21u;                  // 0.0103 in 1/2048 units
}

__device__ __forceinline__ ushort hb(_Float16 h) { return __builtin_bit_cast(ushort, h); }
__device__ __forceinline__ uint umin(uint a, uint b) { return a < b ? a : b; }
__device__ __forceinline__ uint umax(uint a, uint b) { return a > b ? a : b; }

__device__ __forceinline__ void gld16(const void* g, void* l) {
  __builtin_amdgcn_global_load_lds(
      (const __attribute__((address_space(1))) uint*)g,
      (__attribute__((address_space(3))) uint*)l, 16, 0, 0);
}

// ---- kernel 0: E -> pre-swizzled f16 hi/lo (x2048) + enorm + zeros -----------
__global__ __launch_bounds__(64) void vq_prep(const float* __restrict__ emb,
                                              ushort* __restrict__ embPh,
                                              ushort* __restrict__ embPl,
                                              float* __restrict__ enorm,
                                              uint* __restrict__ counts,
                                              uint* __restrict__ flag_count) {
  const int k = blockIdx.x * 64 + threadIdx.x;
  const float4* __restrict__ ep4 = (const float4*)(emb + k * kD);
  uint uh[32], ul[32];
  float s = 0.f;
#pragma unroll
  for (int j = 0; j < kD / 4; ++j) {
    const float4 v = ep4[j];
    s = fmaf(v.x, v.x, s); s = fmaf(v.y, v.y, s);
    s = fmaf(v.z, v.z, s); s = fmaf(v.w, v.w, s);
    const float e0 = v.x * 2048.f, e1 = v.y * 2048.f;
    const float e2 = v.z * 2048.f, e3 = v.w * 2048.f;
    const _Float16 h0 = (_Float16)e0, h1 = (_Float16)e1;
    const _Float16 h2 = (_Float16)e2, h3 = (_Float16)e3;
    const _Float16 l0 = (_Float16)(e0 - (float)h0);
    const _Float16 l1 = (_Float16)(e1 - (float)h1);
    const _Float16 l2 = (_Float16)(e2 - (float)h2);
    const _Float16 l3 = (_Float16)(e3 - (float)h3);
    uh[2 * j] = (uint)hb(h0) | ((uint)hb(h1) << 16);
    uh[2 * j + 1] = (uint)hb(h2) | ((uint)hb(h3) << 16);
    ul[2 * j] = (uint)hb(l0) | ((uint)hb(l1) << 16);
    ul[2 * j + 1] = (uint)hb(l2) | ((uint)hb(l3) << 16);
  }
  // pre-swizzled store: embP[k*128B + (cc^(k&7))*16B] = linear chunk cc
  uint4* __restrict__ ph4 = (uint4*)embPh;
  uint4* __restrict__ pl4 = (uint4*)embPl;
#pragma unroll
  for (int cc = 0; cc < 8; ++cc) {
    const int dst = k * 8 + (cc ^ (k & 7));
    ph4[dst] = uint4{uh[4 * cc], uh[4 * cc + 1], uh[4 * cc + 2], uh[4 * cc + 3]};
    pl4[dst] = uint4{ul[4 * cc], ul[4 * cc + 1], ul[4 * cc + 2], ul[4 * cc + 3]};
  }
  enorm[k] = s;
  counts[k] = 0u;
  if (k == 0) *flag_count = 0u;
}

// ---- kernel 1: MFMA argmin + flags + hist + loss + QUANTIZED WRITE -----------
// Block = 512 thr = 8 waves = 128 points x all 512 codes in 8 dbuf-staged
// 64-code chunks.  Wave (ph=wv>>2, cs=wv&3).  Wave stages ITS OWN 16 rows.
// C/D: col=lane&15 (code), row=(lane>>4)*4+reg (point).
__global__ __launch_bounds__(512, 4) void vq_assign(
    const float* __restrict__ in, const float* __restrict__ emb,
    const ushort* __restrict__ embPh, const ushort* __restrict__ embPl,
    const float* __restrict__ enorm, float* __restrict__ idx_out,
    float* __restrict__ outq, uint* __restrict__ counts,
    float* __restrict__ partial, uint* __restrict__ flag_count,
    uint* __restrict__ flags, uint flag_cap) {
  __shared__ __align__(16) char lds[74240];
  char* __restrict__ xbh = lds;                     // 16 KiB X hi (f16 of -2x)
  char* __restrict__ xbl = lds + 16384;             // 16 KiB X lo
  char* __restrict__ ebh = lds + 32768;             // [2][8192 B] E hi dbuf
  char* __restrict__ ebl = lds + 49152;             // [2][8192 B] E lo dbuf
  uint* __restrict__ mm1 = (uint*)(lds + 65536);    // [4][128]
  uint* __restrict__ mm2 = (uint*)(lds + 67584);    // [4][128]
  float* __restrict__ xnp = (float*)(lds + 69632);  // [4][128]
  uint* __restrict__ hist = (uint*)(lds + 71680);   // [512]
  uint* __restrict__ fidx = (uint*)(lds + 73728);   // [128]
  float* __restrict__ ldsE = (float*)lds;           // epilogue alias (32 KiB,
                                                    // over dead xbh/xbl only)

  const int tid = threadIdx.x;
  const int lane = tid & 63;
  const int wv = __builtin_amdgcn_readfirstlane(tid >> 6);
  const int ph = wv >> 2;    // point-half
  const int cs = wv & 3;     // code-sub (16 codes per 64-code chunk)
  const int c = lane & 15;   // tile col (code)
  const int g = lane >> 4;   // k-chunk group 0..3

  const int blk = blockIdx.x;
  const int bb = blk >> 5;                  // batch
  const int hw0 = (blk & 31) << 7;          // 128 contiguous hw points
  const float* __restrict__ xp = in + (size_t)bb * kCHW + hw0 + ph * 64;

  hist[tid] = 0u;

  // SELF-STAGE: wave (ph,cs) stages rows [cs*16, cs*16+16) of chunk st —
  // exactly the rows it reads.  ph-siblings duplicate identical bytes (benign).
  auto stageE = [&](int buf, int st) {
    const size_t src = (size_t)st * 8192 + cs * 2048;
    const int dst = buf * 8192 + cs * 2048;
#pragma unroll
    for (int i = 0; i < 2; ++i) {
      gld16((const char*)embPh + src + i * 1024 + lane * 16, ebh + dst + i * 1024);
      gld16((const char*)embPl + src + i * 1024 + lane * 16, ebl + dst + i * 1024);
    }
  };
  stageE(0, 0);   // prologue prefetch, flies under X staging

  // scaled+biased C-init per lane for the 8 chunks
  float en_pre[8];
#pragma unroll
  for (int st = 0; st < 8; ++st)
    en_pre[st] = (enorm[st * 64 + cs * 16 + c] + 256.f) * 2048.f;

  // ---- stage X (hi/lo of -2x) + xnorm partial over this wave's 16 dims ----
  {
    const int p = lane;
    uint uh[8], ul[8];
    float xn = 0.f;
#pragma unroll
    for (int j = 0; j < 8; ++j) {
      const float f0 = xp[(size_t)(cs * 16 + 2 * j) * kHW + p];
      const float f1 = xp[(size_t)(cs * 16 + 2 * j + 1) * kHW + p];
      xn = fmaf(f0, f0, xn);
      xn = fmaf(f1, f1, xn);
      const float m0 = -2.f * f0, m1f = -2.f * f1;
      const _Float16 h0 = (_Float16)m0, h1 = (_Float16)m1f;
      const _Float16 l0 = (_Float16)(m0 - (float)h0);
      const _Float16 l1 = (_Float16)(m1f - (float)h1);
      uh[j] = (uint)hb(h0) | ((uint)hb(h1) << 16);
      ul[j] = (uint)hb(l0) | ((uint)hb(l1) << 16);
    }
    const int row = ph * 64 + p;
    const int swz = (row & 7) << 4;
    const int o0 = (row * 128 + cs * 32) ^ swz;
    const int o1 = (row * 128 + cs * 32 + 16) ^ swz;
    *(uint4*)(xbh + o0) = uint4{uh[0], uh[1], uh[2], uh[3]};
    *(uint4*)(xbh + o1) = uint4{uh[4], uh[5], uh[6], uh[7]};
    *(uint4*)(xbl + o0) = uint4{ul[0], ul[1], ul[2], ul[3]};
    *(uint4*)(xbl + o1) = uint4{ul[4], ul[5], ul[6], ul[7]};
    xnp[cs * 128 + row] = xn;
  }
  __syncthreads();   // full drain ONCE: X staged + chunk 0 landed

  uint m1[16], m2[16];
#pragma unroll
  for (int i = 0; i < 16; ++i) { m1[i] = 0xFFFFFFFFu; m2[i] = 0xFFFFFFFFu; }

#pragma unroll
  for (int st = 0; st < 8; ++st) {
    if (st < 7) stageE((st & 1) ^ 1, st + 1);   // prefetch stays in flight

    // counted wait: my own chunk-st loads landed (4 newest = chunk st+1)
    if (st < 7) {
      asm volatile("s_waitcnt vmcnt(4)" ::: "memory");
    } else {
      asm volatile("s_waitcnt vmcnt(0)" ::: "memory");
    }
    __builtin_amdgcn_sched_barrier(0);

    // B-frags: this wave's 16-code slice of the chunk (self-staged)
    const int rowb = cs * 16 + c;
    const int swb = (rowb & 7) << 4;
    const int bbase = (st & 1) * 8192;
    const int ob0 = bbase + ((rowb * 128 + g * 16) ^ swb);
    const int ob1 = bbase + ((rowb * 128 + g * 16 + 64) ^ swb);
    const f16x8 bh0 = *(const f16x8*)(ebh + ob0);
    const f16x8 bh1 = *(const f16x8*)(ebh + ob1);
    const f16x8 bl0 = *(const f16x8*)(ebl + ob0);
    const f16x8 bl1 = *(const f16x8*)(ebl + ob1);
    const float en = en_pre[st];
    const uint kor = (uint)(st * 64 + cs * 16 + c);
    __builtin_amdgcn_s_setprio(1);
#pragma unroll
    for (int rt = 0; rt < 4; ++rt) {
      f16x8 ah[2], al[2];
#pragma unroll
      for (int s = 0; s < 2; ++s) {
        const int row = ph * 64 + rt * 16 + c;
        const int off = (row * 128 + g * 16 + s * 64) ^ ((row & 7) << 4);
        ah[s] = *(const f16x8*)(xbh + off);
        al[s] = *(const f16x8*)(xbl + off);
      }
      // split accumulators: two independent 3-MFMA chains
      f32x4 acc0 = {en, en, en, en};
      f32x4 acc1 = {0.f, 0.f, 0.f, 0.f};
      acc0 = __builtin_amdgcn_mfma_f32_16x16x32_f16(ah[0], bh0, acc0, 0, 0, 0);
      acc1 = __builtin_amdgcn_mfma_f32_16x16x32_f16(ah[1], bh1, acc1, 0, 0, 0);
      acc0 = __builtin_amdgcn_mfma_f32_16x16x32_f16(ah[0], bl0, acc0, 0, 0, 0);
      acc1 = __builtin_amdgcn_mfma_f32_16x16x32_f16(ah[1], bl1, acc1, 0, 0, 0);
      acc0 = __builtin_amdgcn_mfma_f32_16x16x32_f16(al[0], bh0, acc0, 0, 0, 0);
      acc1 = __builtin_amdgcn_mfma_f32_16x16x32_f16(al[1], bh1, acc1, 0, 0, 0);
#pragma unroll
      for (int r = 0; r < 4; ++r) {
        const uint u = ((uint)(acc0[r] + acc1[r]) << 9) | kor;  // fixed-point
        const int i = rt * 4 + r;
        const uint t = umax(m1[i], u);
        m1[i] = umin(m1[i], u);
        m2[i] = umin(m2[i], t);
      }
    }
    __builtin_amdgcn_s_setprio(0);

    // step-end rendezvous WITHOUT vmcnt drain (prefetch stays in flight)
    asm volatile("s_waitcnt lgkmcnt(0)" ::: "memory");
    __builtin_amdgcn_sched_barrier(0);
    __builtin_amdgcn_s_barrier();
  }

  // ---- cross-col butterfly (16 c-lanes per point) ----
#pragma unroll
  for (int i = 0; i < 16; ++i) {
    uint a1 = m1[i], a2 = m2[i];
#pragma unroll
    for (int off = 1; off < 16; off <<= 1) {
      const uint o1 = __shfl_xor(a1, off, 64);
      const uint o2 = __shfl_xor(a2, off, 64);
      const uint t = umax(a1, o1);
      a1 = umin(a1, o1);
      a2 = umin(umin(a2, o2), t);
    }
    m1[i] = a1; m2[i] = a2;
  }

  if (c == 0) {
#pragma unroll
    for (int i = 0; i < 16; ++i) {
      const int p = ph * 64 + (i >> 2) * 16 + g * 4 + (i & 3);
      mm1[cs * 128 + p] = m1[i];
      mm2[cs * 128 + p] = m2[i];
    }
  }
  __syncthreads();

  // ---- cross-wave merge + idx/flags/hist/loss ----
  if (tid < 128) {
    uint a1 = mm1[tid], a2 = mm2[tid];
#pragma unroll
    for (int s = 1; s < 4; ++s) {
      const uint u1 = mm1[s * 128 + tid], u2 = mm2[s * 128 + tid];
      const uint t = umax(a1, u1);
      a1 = umin(a1, u1);
      a2 = umin(umin(a2, u2), t);
    }
    const uint bidx = a1 & 511u;
    fidx[tid] = bidx;
    idx_out[blk * 128 + tid] = (float)bidx;
    if (((a2 >> 9) - (a1 >> 9)) < kGapFP) {   // near-tie -> exact recheck
      const uint slot = atomicAdd(flag_count, 1u);
      if (slot < flag_cap) flags[slot] = (uint)(blk * 128 + tid);
    }
    atomicAdd(&hist[bidx], 1u);

    const float xnorm = (xnp[tid] + xnp[128 + tid]) + (xnp[256 + tid] + xnp[384 + tid]);
    float d2 = fmaf((float)(a1 >> 9), 1.f / 2048.f, -256.f) + xnorm;
#pragma unroll
    for (int off = 32; off > 0; off >>= 1) d2 += __shfl_down(d2, off, 64);
    if ((tid & 63) == 0) partial[blk * 2 + (tid >> 6)] = d2;
  }
  __syncthreads();   // fidx + hist complete; X region (xbh/xbl) now dead
  if (hist[tid]) atomicAdd(&counts[tid], hist[tid]);

  // ---- LDS-transpose epilogue: stage the 128 selected e-rows (coalesced
  // 256 B row fetches) into XOR-swizzled ldsE, then NCHW-coalesced stores.
  // Swizzle: word(p, ch) = p*64 + (ch ^ (((p>>4)&7)<<3)) — float4-safe on
  // write (XOR touches bits>=3 only), 2-way conflicts on read (free, m136).
#pragma unroll
  for (int pass = 0; pass < 4; ++pass) {
    const int r = pass * 32 + (tid >> 4);   // point 0..127
    const int q = tid & 15;                 // float4 quad within the row
    const float4 v = *(const float4*)(emb + fidx[r] * kD + q * 4);
    const int cswz = (q * 4) ^ (((r >> 4) & 7) << 3);
    *(float4*)(ldsE + r * 64 + cswz) = v;
  }
  __syncthreads();
  {
    const int ch = tid >> 3;          // channel 0..63
    const int wq = tid & 7;           // 16-pt chunk 0..7
    float* __restrict__ oq = outq + (size_t)bb * kCHW + (size_t)ch * kHW + hw0 + wq * 16;
    float4 vv[4];
#pragma unroll
    for (int i = 0; i < 16; ++i) {
      const int p = wq * 16 + i;
      const int cswz = ch ^ (((p >> 4) & 7) << 3);
      ((float*)vv)[i] = ldsE[p * 64 + cswz];
    }
#pragma unroll
    for (int i = 0; i < 4; ++i) *(float4*)(oq + i * 4) = vv[i];
  }
}

// ---- kernel 1b: exact f64 re-argmin, ONE WAVE per flagged point; patches
// both idx_out and the quantized output row.
__global__ __launch_bounds__(256) void vq_refine(const float* __restrict__ in,
                                                 const float* __restrict__ emb,
                                                 const uint* __restrict__ flag_count,
                                                 const uint* __restrict__ flags,
                                                 uint flag_cap,
                                                 float* __restrict__ idx_out,
                                                 float* __restrict__ outq) {
  uint cnt = *flag_count;
  if (cnt > flag_cap) cnt = flag_cap;
  const int lane = threadIdx.x & 63;
  const uint wave_id = blockIdx.x * 4u + (threadIdx.x >> 6);
  const uint wave_stride = gridDim.x * 4u;

  for (uint i = wave_id; i < cnt; i += wave_stride) {
    const int n = (int)flags[i];          // wave-uniform
    const int b = n >> 12;
    const int hw = n & 4095;
    const float* __restrict__ xp = in + (size_t)b * kCHW + hw;

    float xr[kD];
#pragma unroll
    for (int d = 0; d < kD; ++d) xr[d] = xp[(size_t)d * kHW];

    double best = 1e300;
    int bidx = 0;
#pragma unroll 1
    for (int kk = 0; kk < 8; ++kk) {
      const int k = lane * 8 + kk;
      const float4* __restrict__ ep4 = (const float4*)(emb + k * kD);
      double s0 = 0.0, s1 = 0.0;
#pragma unroll
      for (int j = 0; j < kD / 4; ++j) {
        const float4 e = ep4[j];
        const double d0 = (double)xr[4 * j + 0] - (double)e.x;
        const double d1 = (double)xr[4 * j + 1] - (double)e.y;
        const double d2 = (double)xr[4 * j + 2] - (double)e.z;
        const double d3 = (double)xr[4 * j + 3] - (double)e.w;
        s0 = fma(d0, d0, s0);
        s1 = fma(d1, d1, s1);
        s0 = fma(d2, d2, s0);
        s1 = fma(d3, d3, s1);
      }
      const double s = s0 + s1;
      if (s < best) { best = s; bidx = k; }  // strict < == first-min in-lane
    }
#pragma unroll
    for (int off = 32; off > 0; off >>= 1) {
      const double ob = __shfl_xor(best, off, 64);
      const int oi = __shfl_xor(bidx, off, 64);
      if (ob < best || (ob == best && oi < bidx)) { best = ob; bidx = oi; }
    }
    if (lane == 0) idx_out[n] = (float)bidx;
    // patch quantized row: lane = channel
    outq[(size_t)b * kCHW + (size_t)lane * kHW + hw] = emb[bidx * kD + lane];
  }
}

// ---- kernel 2: scalars (loss, perplexity, usage) -----------------------------
__global__ __launch_bounds__(512) void vq_finalize(const float* __restrict__ weight,
                                                   const uint* __restrict__ counts,
                                                   const float* __restrict__ partial,
                                                   float* __restrict__ out_scalars) {
  __shared__ float red[512];
  const int t = threadIdx.x;

  const float avg = (float)counts[t] / (float)kN;
  red[t] = avg * logf(avg + 1e-10f);
  __syncthreads();
#pragma unroll
  for (int off = 256; off > 0; off >>= 1) {
    if (t < off) red[t] += red[t + off];
    __syncthreads();
  }
  const float perp = expf(-red[0]);
  __syncthreads();

  // 2048 loss partials, fixed order -> deterministic
  red[t] = (partial[t] + partial[t + 512]) + (partial[t + 1024] + partial[t + 1536]);
  __syncthreads();
#pragma unroll
  for (int off = 256; off > 0; off >>= 1) {
    if (t < off) red[t] += red[t + off];
    __syncthreads();
  }
  const float loss = red[0] / (float)((long long)kN * (long long)kD);
  __syncthreads();

  red[t] = (weight[t] >= 0.01f) ? 1.f : 0.f;
  __syncthreads();
#pragma unroll
  for (int off = 256; off > 0; off >>= 1) {
    if (t < off) red[t] += red[t + off];
    __syncthreads();
  }
  if (t == 0) {
    out_scalars[0] = loss;
    out_scalars[1] = perp;
    out_scalars[2] = red[0];
  }
}

extern "C" void kernel_launch(void* const* d_in, const int* in_sizes, int n_in,
                              void* d_out, int out_size, void* d_ws, size_t ws_size,
                              hipStream_t stream) {
  const float* in = (const float*)d_in[0];
  const float* emb = (const float*)d_in[1];
  const float* weight = (const float*)d_in[2];
  float* out = (float*)d_out;

  // workspace layout (4 B units)
  float* ws_f = (float*)d_ws;
  uint* ws_u = (uint*)d_ws;
  ushort* embPh = (ushort*)d_ws;            // 64 KiB  -> u32 [0, 16384)
  ushort* embPl = embPh + kK * kD;          // 64 KiB  -> u32 [16384, 32768)
  float* enorm = ws_f + 65536;              // [512]
  uint* counts = ws_u + 66048;              // [512]
  float* partial = ws_f + 66560;            // [2048]
  uint* flag_count = ws_u + 68608;          // [1]
  uint* flags = ws_u + 68609;               // [flag_cap]
  const size_t ws_elems = ws_size / 4;
  const uint flag_cap =
      (ws_elems > 68609)
          ? (uint)((ws_elems - 68609 < (size_t)kN) ? ws_elems - 68609 : (size_t)kN)
          : 0u;

  float* outq = out;                    // [8388608]
  float* out_scalars = out + kQElems;   // [3]
  float* idx_out = out + kQElems + 3;   // [131072]

  vq_prep<<<8, 64, 0, stream>>>(emb, embPh, embPl, enorm, counts, flag_count);
  vq_assign<<<kN / 128, 512, 0, stream>>>(in, emb, embPh, embPl, enorm, idx_out,
                                          outq, counts, partial, flag_count, flags,
                                          flag_cap);
  vq_refine<<<256, 256, 0, stream>>>(in, emb, flag_count, flags, flag_cap,
                                     idx_out, outq);
  vq_finalize<<<1, 512, 0, stream>>>(weight, counts, partial, out_scalars);
}

// Round 21
// 83.978 us; speedup vs baseline: 1.4672x; 1.0460x over previous
//
#include <hip/hip_runtime.h>

// VectorQuantizer on MI355X (gfx950) — async-pipelined MFMA argmin (counted
// vmcnt, raw s_barrier) + LDS-transpose fused quantized write; f64 refine
// patches near-ties.  R21 = r20 (best: 87.8 us) with vq_finalize FOLDED into
// the refine dispatch (grid 257: blocks 0..255 refine, block 256 finalize) —
// finalize depends only on assign's outputs, so it runs concurrently with
// refine and one launch+gap disappears.
//
// Distance core: s = ||e||^2 - 2 x.e.  E pre-scaled by 2048, f16 hi/lo split,
// PRE-SWIZZLED in ws (per-lane gld16 source, linear LDS dest).  X = f16 hi/lo
// of (-2x).  3-term MFMA (xh.eh + xh.el + xl.eh), split accumulators.
// C-init = (||e||^2+256)*2048; packed key ((uint)acc << 9) | idx -> u32-min
// argmin, first-min tie-break.  Near-ties (gap < 21/2048) re-solved in f64 by
// vq_refine (patches idx AND quantized rows).  Loss/hist pre-refine.

typedef __attribute__((ext_vector_type(8))) _Float16 f16x8;
typedef __attribute__((ext_vector_type(4))) float f32x4;
typedef unsigned int uint;
typedef unsigned short ushort;

namespace {
constexpr int kC = 64, kH = 64, kW = 64;
constexpr int kK = 512, kD = 64;
constexpr int kHW = kH * kW;                  // 4096
constexpr int kCHW = kC * kHW;                // 262144
constexpr int kN = 32 * kHW;                  // 131072
constexpr int kQElems = 32 * kC * kHW;        // 8388608
constexpr uint kGapFP = 21u;                  // 0.0103 in 1/2048 units
}

__device__ __forceinline__ ushort hb(_Float16 h) { return __builtin_bit_cast(ushort, h); }
__device__ __forceinline__ uint umin(uint a, uint b) { return a < b ? a : b; }
__device__ __forceinline__ uint umax(uint a, uint b) { return a > b ? a : b; }

__device__ __forceinline__ void gld16(const void* g, void* l) {
  __builtin_amdgcn_global_load_lds(
      (const __attribute__((address_space(1))) uint*)g,
      (__attribute__((address_space(3))) uint*)l, 16, 0, 0);
}

// ---- kernel 0: E -> pre-swizzled f16 hi/lo (x2048) + enorm + zeros -----------
__global__ __launch_bounds__(64) void vq_prep(const float* __restrict__ emb,
                                              ushort* __restrict__ embPh,
                                              ushort* __restrict__ embPl,
                                              float* __restrict__ enorm,
                                              uint* __restrict__ counts,
                                              uint* __restrict__ flag_count) {
  const int k = blockIdx.x * 64 + threadIdx.x;
  const float4* __restrict__ ep4 = (const float4*)(emb + k * kD);
  uint uh[32], ul[32];
  float s = 0.f;
#pragma unroll
  for (int j = 0; j < kD / 4; ++j) {
    const float4 v = ep4[j];
    s = fmaf(v.x, v.x, s); s = fmaf(v.y, v.y, s);
    s = fmaf(v.z, v.z, s); s = fmaf(v.w, v.w, s);
    const float e0 = v.x * 2048.f, e1 = v.y * 2048.f;
    const float e2 = v.z * 2048.f, e3 = v.w * 2048.f;
    const _Float16 h0 = (_Float16)e0, h1 = (_Float16)e1;
    const _Float16 h2 = (_Float16)e2, h3 = (_Float16)e3;
    const _Float16 l0 = (_Float16)(e0 - (float)h0);
    const _Float16 l1 = (_Float16)(e1 - (float)h1);
    const _Float16 l2 = (_Float16)(e2 - (float)h2);
    const _Float16 l3 = (_Float16)(e3 - (float)h3);
    uh[2 * j] = (uint)hb(h0) | ((uint)hb(h1) << 16);
    uh[2 * j + 1] = (uint)hb(h2) | ((uint)hb(h3) << 16);
    ul[2 * j] = (uint)hb(l0) | ((uint)hb(l1) << 16);
    ul[2 * j + 1] = (uint)hb(l2) | ((uint)hb(l3) << 16);
  }
  // pre-swizzled store: embP[k*128B + (cc^(k&7))*16B] = linear chunk cc
  uint4* __restrict__ ph4 = (uint4*)embPh;
  uint4* __restrict__ pl4 = (uint4*)embPl;
#pragma unroll
  for (int cc = 0; cc < 8; ++cc) {
    const int dst = k * 8 + (cc ^ (k & 7));
    ph4[dst] = uint4{uh[4 * cc], uh[4 * cc + 1], uh[4 * cc + 2], uh[4 * cc + 3]};
    pl4[dst] = uint4{ul[4 * cc], ul[4 * cc + 1], ul[4 * cc + 2], ul[4 * cc + 3]};
  }
  enorm[k] = s;
  counts[k] = 0u;
  if (k == 0) *flag_count = 0u;
}

// ---- kernel 1: MFMA argmin + flags + hist + loss + QUANTIZED WRITE -----------
// Block = 512 thr = 8 waves = 128 points x all 512 codes in 8 dbuf-staged
// 64-code chunks.  Wave (ph=wv>>2, cs=wv&3).  Wave stages ITS OWN 16 rows.
// C/D: col=lane&15 (code), row=(lane>>4)*4+reg (point).
__global__ __launch_bounds__(512, 4) void vq_assign(
    const float* __restrict__ in, const float* __restrict__ emb,
    const ushort* __restrict__ embPh, const ushort* __restrict__ embPl,
    const float* __restrict__ enorm, float* __restrict__ idx_out,
    float* __restrict__ outq, uint* __restrict__ counts,
    float* __restrict__ partial, uint* __restrict__ flag_count,
    uint* __restrict__ flags, uint flag_cap) {
  __shared__ __align__(16) char lds[74240];
  char* __restrict__ xbh = lds;                     // 16 KiB X hi (f16 of -2x)
  char* __restrict__ xbl = lds + 16384;             // 16 KiB X lo
  char* __restrict__ ebh = lds + 32768;             // [2][8192 B] E hi dbuf
  char* __restrict__ ebl = lds + 49152;             // [2][8192 B] E lo dbuf
  uint* __restrict__ mm1 = (uint*)(lds + 65536);    // [4][128]
  uint* __restrict__ mm2 = (uint*)(lds + 67584);    // [4][128]
  float* __restrict__ xnp = (float*)(lds + 69632);  // [4][128]
  uint* __restrict__ hist = (uint*)(lds + 71680);   // [512]
  uint* __restrict__ fidx = (uint*)(lds + 73728);   // [128]
  float* __restrict__ ldsE = (float*)lds;           // epilogue alias (32 KiB,
                                                    // over dead xbh/xbl only)

  const int tid = threadIdx.x;
  const int lane = tid & 63;
  const int wv = __builtin_amdgcn_readfirstlane(tid >> 6);
  const int ph = wv >> 2;    // point-half
  const int cs = wv & 3;     // code-sub (16 codes per 64-code chunk)
  const int c = lane & 15;   // tile col (code)
  const int g = lane >> 4;   // k-chunk group 0..3

  const int blk = blockIdx.x;
  const int bb = blk >> 5;                  // batch
  const int hw0 = (blk & 31) << 7;          // 128 contiguous hw points
  const float* __restrict__ xp = in + (size_t)bb * kCHW + hw0 + ph * 64;

  hist[tid] = 0u;

  // SELF-STAGE: wave (ph,cs) stages rows [cs*16, cs*16+16) of chunk st —
  // exactly the rows it reads.  ph-siblings duplicate identical bytes (benign).
  auto stageE = [&](int buf, int st) {
    const size_t src = (size_t)st * 8192 + cs * 2048;
    const int dst = buf * 8192 + cs * 2048;
#pragma unroll
    for (int i = 0; i < 2; ++i) {
      gld16((const char*)embPh + src + i * 1024 + lane * 16, ebh + dst + i * 1024);
      gld16((const char*)embPl + src + i * 1024 + lane * 16, ebl + dst + i * 1024);
    }
  };
  stageE(0, 0);   // prologue prefetch, flies under X staging

  // scaled+biased C-init per lane for the 8 chunks
  float en_pre[8];
#pragma unroll
  for (int st = 0; st < 8; ++st)
    en_pre[st] = (enorm[st * 64 + cs * 16 + c] + 256.f) * 2048.f;

  // ---- stage X (hi/lo of -2x) + xnorm partial over this wave's 16 dims ----
  {
    const int p = lane;
    uint uh[8], ul[8];
    float xn = 0.f;
#pragma unroll
    for (int j = 0; j < 8; ++j) {
      const float f0 = xp[(size_t)(cs * 16 + 2 * j) * kHW + p];
      const float f1 = xp[(size_t)(cs * 16 + 2 * j + 1) * kHW + p];
      xn = fmaf(f0, f0, xn);
      xn = fmaf(f1, f1, xn);
      const float m0 = -2.f * f0, m1f = -2.f * f1;
      const _Float16 h0 = (_Float16)m0, h1 = (_Float16)m1f;
      const _Float16 l0 = (_Float16)(m0 - (float)h0);
      const _Float16 l1 = (_Float16)(m1f - (float)h1);
      uh[j] = (uint)hb(h0) | ((uint)hb(h1) << 16);
      ul[j] = (uint)hb(l0) | ((uint)hb(l1) << 16);
    }
    const int row = ph * 64 + p;
    const int swz = (row & 7) << 4;
    const int o0 = (row * 128 + cs * 32) ^ swz;
    const int o1 = (row * 128 + cs * 32 + 16) ^ swz;
    *(uint4*)(xbh + o0) = uint4{uh[0], uh[1], uh[2], uh[3]};
    *(uint4*)(xbh + o1) = uint4{uh[4], uh[5], uh[6], uh[7]};
    *(uint4*)(xbl + o0) = uint4{ul[0], ul[1], ul[2], ul[3]};
    *(uint4*)(xbl + o1) = uint4{ul[4], ul[5], ul[6], ul[7]};
    xnp[cs * 128 + row] = xn;
  }
  __syncthreads();   // full drain ONCE: X staged + chunk 0 landed

  uint m1[16], m2[16];
#pragma unroll
  for (int i = 0; i < 16; ++i) { m1[i] = 0xFFFFFFFFu; m2[i] = 0xFFFFFFFFu; }

#pragma unroll
  for (int st = 0; st < 8; ++st) {
    if (st < 7) stageE((st & 1) ^ 1, st + 1);   // prefetch stays in flight

    // counted wait: my own chunk-st loads landed (4 newest = chunk st+1)
    if (st < 7) {
      asm volatile("s_waitcnt vmcnt(4)" ::: "memory");
    } else {
      asm volatile("s_waitcnt vmcnt(0)" ::: "memory");
    }
    __builtin_amdgcn_sched_barrier(0);

    // B-frags: this wave's 16-code slice of the chunk (self-staged)
    const int rowb = cs * 16 + c;
    const int swb = (rowb & 7) << 4;
    const int bbase = (st & 1) * 8192;
    const int ob0 = bbase + ((rowb * 128 + g * 16) ^ swb);
    const int ob1 = bbase + ((rowb * 128 + g * 16 + 64) ^ swb);
    const f16x8 bh0 = *(const f16x8*)(ebh + ob0);
    const f16x8 bh1 = *(const f16x8*)(ebh + ob1);
    const f16x8 bl0 = *(const f16x8*)(ebl + ob0);
    const f16x8 bl1 = *(const f16x8*)(ebl + ob1);
    const float en = en_pre[st];
    const uint kor = (uint)(st * 64 + cs * 16 + c);
    __builtin_amdgcn_s_setprio(1);
#pragma unroll
    for (int rt = 0; rt < 4; ++rt) {
      f16x8 ah[2], al[2];
#pragma unroll
      for (int s = 0; s < 2; ++s) {
        const int row = ph * 64 + rt * 16 + c;
        const int off = (row * 128 + g * 16 + s * 64) ^ ((row & 7) << 4);
        ah[s] = *(const f16x8*)(xbh + off);
        al[s] = *(const f16x8*)(xbl + off);
      }
      // split accumulators: two independent 3-MFMA chains
      f32x4 acc0 = {en, en, en, en};
      f32x4 acc1 = {0.f, 0.f, 0.f, 0.f};
      acc0 = __builtin_amdgcn_mfma_f32_16x16x32_f16(ah[0], bh0, acc0, 0, 0, 0);
      acc1 = __builtin_amdgcn_mfma_f32_16x16x32_f16(ah[1], bh1, acc1, 0, 0, 0);
      acc0 = __builtin_amdgcn_mfma_f32_16x16x32_f16(ah[0], bl0, acc0, 0, 0, 0);
      acc1 = __builtin_amdgcn_mfma_f32_16x16x32_f16(ah[1], bl1, acc1, 0, 0, 0);
      acc0 = __builtin_amdgcn_mfma_f32_16x16x32_f16(al[0], bh0, acc0, 0, 0, 0);
      acc1 = __builtin_amdgcn_mfma_f32_16x16x32_f16(al[1], bh1, acc1, 0, 0, 0);
#pragma unroll
      for (int r = 0; r < 4; ++r) {
        const uint u = ((uint)(acc0[r] + acc1[r]) << 9) | kor;  // fixed-point
        const int i = rt * 4 + r;
        const uint t = umax(m1[i], u);
        m1[i] = umin(m1[i], u);
        m2[i] = umin(m2[i], t);
      }
    }
    __builtin_amdgcn_s_setprio(0);

    // step-end rendezvous WITHOUT vmcnt drain (prefetch stays in flight)
    asm volatile("s_waitcnt lgkmcnt(0)" ::: "memory");
    __builtin_amdgcn_sched_barrier(0);
    __builtin_amdgcn_s_barrier();
  }

  // ---- cross-col butterfly (16 c-lanes per point) ----
#pragma unroll
  for (int i = 0; i < 16; ++i) {
    uint a1 = m1[i], a2 = m2[i];
#pragma unroll
    for (int off = 1; off < 16; off <<= 1) {
      const uint o1 = __shfl_xor(a1, off, 64);
      const uint o2 = __shfl_xor(a2, off, 64);
      const uint t = umax(a1, o1);
      a1 = umin(a1, o1);
      a2 = umin(umin(a2, o2), t);
    }
    m1[i] = a1; m2[i] = a2;
  }

  if (c == 0) {
#pragma unroll
    for (int i = 0; i < 16; ++i) {
      const int p = ph * 64 + (i >> 2) * 16 + g * 4 + (i & 3);
      mm1[cs * 128 + p] = m1[i];
      mm2[cs * 128 + p] = m2[i];
    }
  }
  __syncthreads();

  // ---- cross-wave merge + idx/flags/hist/loss ----
  if (tid < 128) {
    uint a1 = mm1[tid], a2 = mm2[tid];
#pragma unroll
    for (int s = 1; s < 4; ++s) {
      const uint u1 = mm1[s * 128 + tid], u2 = mm2[s * 128 + tid];
      const uint t = umax(a1, u1);
      a1 = umin(a1, u1);
      a2 = umin(umin(a2, u2), t);
    }
    const uint bidx = a1 & 511u;
    fidx[tid] = bidx;
    idx_out[blk * 128 + tid] = (float)bidx;
    if (((a2 >> 9) - (a1 >> 9)) < kGapFP) {   // near-tie -> exact recheck
      const uint slot = atomicAdd(flag_count, 1u);
      if (slot < flag_cap) flags[slot] = (uint)(blk * 128 + tid);
    }
    atomicAdd(&hist[bidx], 1u);

    const float xnorm = (xnp[tid] + xnp[128 + tid]) + (xnp[256 + tid] + xnp[384 + tid]);
    float d2 = fmaf((float)(a1 >> 9), 1.f / 2048.f, -256.f) + xnorm;
#pragma unroll
    for (int off = 32; off > 0; off >>= 1) d2 += __shfl_down(d2, off, 64);
    if ((tid & 63) == 0) partial[blk * 2 + (tid >> 6)] = d2;
  }
  __syncthreads();   // fidx + hist complete; X region (xbh/xbl) now dead
  if (hist[tid]) atomicAdd(&counts[tid], hist[tid]);

  // ---- LDS-transpose epilogue: stage the 128 selected e-rows (coalesced
  // 256 B row fetches) into XOR-swizzled ldsE, then NCHW-coalesced stores.
#pragma unroll
  for (int pass = 0; pass < 4; ++pass) {
    const int r = pass * 32 + (tid >> 4);   // point 0..127
    const int q = tid & 15;                 // float4 quad within the row
    const float4 v = *(const float4*)(emb + fidx[r] * kD + q * 4);
    const int cswz = (q * 4) ^ (((r >> 4) & 7) << 3);
    *(float4*)(ldsE + r * 64 + cswz) = v;
  }
  __syncthreads();
  {
    const int ch = tid >> 3;          // channel 0..63
    const int wq = tid & 7;           // 16-pt chunk 0..7
    float* __restrict__ oq = outq + (size_t)bb * kCHW + (size_t)ch * kHW + hw0 + wq * 16;
    float4 vv[4];
#pragma unroll
    for (int i = 0; i < 16; ++i) {
      const int p = wq * 16 + i;
      const int cswz = ch ^ (((p >> 4) & 7) << 3);
      ((float*)vv)[i] = ldsE[p * 64 + cswz];
    }
#pragma unroll
    for (int i = 0; i < 4; ++i) *(float4*)(oq + i * 4) = vv[i];
  }
}

// ---- kernel 1b: refine (blocks 0..255) + finalize (block 256), one dispatch --
// Refine: exact f64 re-argmin, ONE WAVE per flagged point; patches idx_out and
// the quantized row.  Finalize: loss/perplexity/usage from assign's outputs
// (independent of refine -> runs concurrently).
__global__ __launch_bounds__(256) void vq_refine_fin(
    const float* __restrict__ in, const float* __restrict__ emb,
    const float* __restrict__ weight, const uint* __restrict__ flag_count,
    const uint* __restrict__ flags, uint flag_cap, float* __restrict__ idx_out,
    float* __restrict__ outq, const uint* __restrict__ counts,
    const float* __restrict__ partial, float* __restrict__ out_scalars) {
  if (blockIdx.x == 256) {
    // ---- finalize: 256 threads, fixed-order reductions (deterministic) ----
    __shared__ float red[256];
    const int t = threadIdx.x;

    // perplexity = exp(-sum(avg * log(avg + 1e-10)))
    {
      const float a0 = (float)counts[t] / (float)kN;
      const float a1 = (float)counts[t + 256] / (float)kN;
      red[t] = a0 * logf(a0 + 1e-10f) + a1 * logf(a1 + 1e-10f);
    }
    __syncthreads();
#pragma unroll
    for (int off = 128; off > 0; off >>= 1) {
      if (t < off) red[t] += red[t + off];
      __syncthreads();
    }
    const float perp = expf(-red[0]);
    __syncthreads();

    // loss: 2048 partials, fixed order
    {
      float a = 0.f;
#pragma unroll
      for (int j = 0; j < 8; ++j) a += partial[t + 256 * j];
      red[t] = a;
    }
    __syncthreads();
#pragma unroll
    for (int off = 128; off > 0; off >>= 1) {
      if (t < off) red[t] += red[t + off];
      __syncthreads();
    }
    const float loss = red[0] / (float)((long long)kN * (long long)kD);
    __syncthreads();

    // usage = sum(weight >= 0.01)
    red[t] = ((weight[t] >= 0.01f) ? 1.f : 0.f) +
             ((weight[t + 256] >= 0.01f) ? 1.f : 0.f);
    __syncthreads();
#pragma unroll
    for (int off = 128; off > 0; off >>= 1) {
      if (t < off) red[t] += red[t + off];
      __syncthreads();
    }
    if (t == 0) {
      out_scalars[0] = loss;
      out_scalars[1] = perp;
      out_scalars[2] = red[0];
    }
    return;
  }

  // ---- refine blocks ----
  uint cnt = *flag_count;
  if (cnt > flag_cap) cnt = flag_cap;
  const int lane = threadIdx.x & 63;
  const uint wave_id = blockIdx.x * 4u + (threadIdx.x >> 6);
  const uint wave_stride = 256u * 4u;

  for (uint i = wave_id; i < cnt; i += wave_stride) {
    const int n = (int)flags[i];          // wave-uniform
    const int b = n >> 12;
    const int hw = n & 4095;
    const float* __restrict__ xp = in + (size_t)b * kCHW + hw;

    float xr[kD];
#pragma unroll
    for (int d = 0; d < kD; ++d) xr[d] = xp[(size_t)d * kHW];

    double best = 1e300;
    int bidx = 0;
#pragma unroll 1
    for (int kk = 0; kk < 8; ++kk) {
      const int k = lane * 8 + kk;
      const float4* __restrict__ ep4 = (const float4*)(emb + k * kD);
      double s0 = 0.0, s1 = 0.0;
#pragma unroll
      for (int j = 0; j < kD / 4; ++j) {
        const float4 e = ep4[j];
        const double d0 = (double)xr[4 * j + 0] - (double)e.x;
        const double d1 = (double)xr[4 * j + 1] - (double)e.y;
        const double d2 = (double)xr[4 * j + 2] - (double)e.z;
        const double d3 = (double)xr[4 * j + 3] - (double)e.w;
        s0 = fma(d0, d0, s0);
        s1 = fma(d1, d1, s1);
        s0 = fma(d2, d2, s0);
        s1 = fma(d3, d3, s1);
      }
      const double s = s0 + s1;
      if (s < best) { best = s; bidx = k; }  // strict < == first-min in-lane
    }
#pragma unroll
    for (int off = 32; off > 0; off >>= 1) {
      const double ob = __shfl_xor(best, off, 64);
      const int oi = __shfl_xor(bidx, off, 64);
      if (ob < best || (ob == best && oi < bidx)) { best = ob; bidx = oi; }
    }
    if (lane == 0) idx_out[n] = (float)bidx;
    // patch quantized row: lane = channel
    outq[(size_t)b * kCHW + (size_t)lane * kHW + hw] = emb[bidx * kD + lane];
  }
}

extern "C" void kernel_launch(void* const* d_in, const int* in_sizes, int n_in,
                              void* d_out, int out_size, void* d_ws, size_t ws_size,
                              hipStream_t stream) {
  const float* in = (const float*)d_in[0];
  const float* emb = (const float*)d_in[1];
  const float* weight = (const float*)d_in[2];
  float* out = (float*)d_out;

  // workspace layout (4 B units)
  float* ws_f = (float*)d_ws;
  uint* ws_u = (uint*)d_ws;
  ushort* embPh = (ushort*)d_ws;            // 64 KiB  -> u32 [0, 16384)
  ushort* embPl = embPh + kK * kD;          // 64 KiB  -> u32 [16384, 32768)
  float* enorm = ws_f + 65536;              // [512]
  uint* counts = ws_u + 66048;              // [512]
  float* partial = ws_f + 66560;            // [2048]
  uint* flag_count = ws_u + 68608;          // [1]
  uint* flags = ws_u + 68609;               // [flag_cap]
  const size_t ws_elems = ws_size / 4;
  const uint flag_cap =
      (ws_elems > 68609)
          ? (uint)((ws_elems - 68609 < (size_t)kN) ? ws_elems - 68609 : (size_t)kN)
          : 0u;

  float* outq = out;                    // [8388608]
  float* out_scalars = out + kQElems;   // [3]
  float* idx_out = out + kQElems + 3;   // [131072]

  vq_prep<<<8, 64, 0, stream>>>(emb, embPh, embPl, enorm, counts, flag_count);
  vq_assign<<<kN / 128, 512, 0, stream>>>(in, emb, embPh, embPl, enorm, idx_out,
                                          outq, counts, partial, flag_count, flags,
                                          flag_cap);
  vq_refine_fin<<<257, 256, 0, stream>>>(in, emb, weight, flag_count, flags,
                                         flag_cap, idx_out, outq, counts, partial,
                                         out_scalars);
}